// Round 10
// baseline (534.729 us; speedup 1.0000x reference)
//
#include <hip/hip_runtime.h>
#include <hip/hip_bf16.h>
#include <cstdint>
#include <cstddef>

// ---------------------------------------------------------------------------
// HopfieldModel: z = x@W_enc; 4x { q <- softmax(2 q K^T) K } per network;
// out = log_softmax(relu(concat q) @ W_lin + b_lin)
//
// scan v3 (fp16 MFMA, software-pipelined single pass):
//   - pairs of 16-key slices double-buffered: load pair p+1 while MFMA pair p
//     (round-9 lesson: compiler-scheduled loads were fully serialized at
//     ~560cyc/load; 36K cycles/wave for 64 loads).
//   - emit per 4-slice group against a running PER-WAVE threshold
//     (run_max <= G  =>  every key with s >= G-9.5 is emitted; validated
//     structure in rounds 5-9, absmax 0).
//   - dispatch-window XCD swizzle: id = 64*window + 8*qt + xcd,
//     chunk = 8*window + xcd  =>  the 8 qt-blocks of a chunk are adjacent in
//     dispatch AND share one XCD L2 (round-9 lesson: same-XCD but time-
//     separated readers evicted the chunk; FETCH 18->44MB).
//   - chunk max still published to cmaxb (LDS atomicMax at the end) so refine
//     can skip irrelevant chunks / rescan overflowed ones.
// refine: G = max stored chunk max; skip chunks with cmax < G-9.75; stored
//   candidates filtered at G-9.5; overflowed relevant chunks get an exact
//   fp32 rescan of JUST that 1024-key chunk; survivors exactly rescored in
//   fp32; exact softmax + PV.  (unchanged from round 8/9)
// ---------------------------------------------------------------------------

#define NNET 4
#define NQ   256
#define EDIM 128
#define NKEY 32768
#define ESTR 129              // embeddings row stride (col 128 dropped)
#define QT   32               // q rows per scan block
#define NCHUNK 32
#define KPC  (NKEY/NCHUNK)    // 1024 keys per chunk
#define SCAN_WAVES 4
#define KPW  (KPC/SCAN_WAVES) // 256 keys per wave
#define SLICES (KPW/16)       // 16 slices of 16 keys
#define SROW (QT/16)          // 2 row-tiles of 16 q rows
#define BLOCKCAP 32           // cand slots per (query, chunk)
#define SURV_CAP 512
#define EMIT_MARGIN 10.0f     // emission band below running wave max
#define SEL_MARGIN  9.5f      // stored-score filter below global max
#define REL_MARGIN  9.75f     // chunk relevance: cmax >= G - REL
#define RESCAN_MARGIN 10.0f   // exact-score filter for rescanned chunks

typedef _Float16 half8 __attribute__((ext_vector_type(8)));
typedef float f32x4v __attribute__((ext_vector_type(4)));

__device__ __forceinline__ float dec16(unsigned v) {
  _Float16 h = __builtin_bit_cast(_Float16, (unsigned short)(v & 0xFFFFu));
  return (float)h;
}
__device__ __forceinline__ unsigned pack16(int key, float s) {
  unsigned short hb = __builtin_bit_cast(unsigned short, (_Float16)s);
  return ((unsigned)key << 16) | (unsigned)hb;
}
__device__ __forceinline__ unsigned enc_f32(float f) {
  unsigned u = __float_as_uint(f);
  return (u & 0x80000000u) ? ~u : (u | 0x80000000u);  // order-preserving
}
__device__ __forceinline__ float dec_f32(unsigned e) {
  unsigned u = (e & 0x80000000u) ? (e & 0x7FFFFFFFu) : ~e;
  return __uint_as_float(u);
}

// --------------------------- encoder: z = x@We + be -------------------------
__global__ __launch_bounds__(128)
void enc_kernel(const float* __restrict__ x, const float* __restrict__ We,
                const float* __restrict__ be, float* __restrict__ q0) {
  const int b = blockIdx.x, tid = threadIdx.x;
  __shared__ float xs[784];
  for (int i = tid; i < 784; i += 128) xs[i] = x[b * 784 + i];
  __syncthreads();
  float acc = be[tid];
  for (int i = 0; i < 784; ++i) acc += xs[i] * We[i * EDIM + tid];
#pragma unroll
  for (int n = 0; n < NNET; ++n) q0[((size_t)n * NQ + b) * EDIM + tid] = acc;
}

// ------------------- keyprep: embeddings f32 -> fp16 (drop col 128) --------
typedef _Float16 half4v __attribute__((ext_vector_type(4)));
__global__ __launch_bounds__(256)
void keyprep_kernel(const float* __restrict__ emb, _Float16* __restrict__ kh) {
  const size_t quads = (size_t)NNET * NKEY * EDIM / 4;
  for (size_t i4 = (size_t)blockIdx.x * 256 + threadIdx.x; i4 < quads;
       i4 += (size_t)gridDim.x * 256) {
    const size_t row = i4 >> 5;
    const int col = (int)(i4 & 31) * 4;
    const float* src = emb + row * ESTR + col;
    half4v h;
#pragma unroll
    for (int j = 0; j < 4; ++j) h[j] = (_Float16)src[j];
    *(half4v*)(kh + i4 * 4) = h;
  }
}

// ------------------------------- scan --------------------------------------
// 1024 blocks (1D), 256 threads = 4 waves, each wave owns 256 keys.
// Block remap: wg = 64*window + 8*qt + xcd; chunk-group c = 8*window + xcd.
template <bool F16K>
__global__ __launch_bounds__(SCAN_WAVES * 64)
void scan_kernel(const float* __restrict__ qcur, const float* __restrict__ emb,
                 const _Float16* __restrict__ keysh,
                 int* __restrict__ cntb, float* __restrict__ cmaxb,
                 unsigned* __restrict__ cand) {
  const int wg = blockIdx.x;
  const int window = wg >> 6;        // 16 windows of 64 blocks
  const int within = wg & 63;
  const int xcd = within & 7;
  const int qt = within >> 3;        // 0..7
  const int c = window * 8 + xcd;    // 0..127
  const int net = c >> 5, chunk = c & 31;

  const int tid = threadIdx.x;
  const int lane = tid & 63;
  const int g = lane >> 4, ln = lane & 15;

  __shared__ unsigned lmax[QT];
  __shared__ int lcnt[QT];
  __shared__ unsigned lbuf[QT][BLOCKCAP];
  if (tid < QT) { lmax[tid] = enc_f32(-3.4e38f); lcnt[tid] = 0; }

  // Q A-fragments (16x16x32: lane holds row m=lane&15, k = 8*(lane>>4)+j),
  // beta=2 folded into q.
  half8 aq[SROW][4];
  {
    const float* qb = qcur + ((size_t)net * NQ + qt * QT) * EDIM;
#pragma unroll
    for (int s = 0; s < SROW; ++s)
#pragma unroll
      for (int f = 0; f < 4; ++f) {
        const float* p = qb + (s * 16 + ln) * EDIM + f * 32 + g * 8;
        half8 h;
#pragma unroll
        for (int j = 0; j < 8; ++j) h[j] = (_Float16)(2.0f * p[j]);
        aq[s][f] = h;
      }
  }
  __syncthreads();

  const int w = tid >> 6;
  const int key0 = chunk * KPC + w * KPW;

  // load one PAIR of slices (2*p, 2*p+1) into buf[2][4] (8 x 16B loads)
  auto loadPair = [&](int p, half8 buf[2][4]) {
#pragma unroll
    for (int u = 0; u < 2; ++u) {
      const int sl = 2 * p + u;
      const size_t keyrow = (size_t)net * NKEY + key0 + sl * 16 + ln;
      if constexpr (F16K) {
        const _Float16* kp = keysh + keyrow * EDIM + g * 8;
#pragma unroll
        for (int f = 0; f < 4; ++f) buf[u][f] = *(const half8*)(kp + f * 32);
      } else {
        const float* kp = emb + keyrow * ESTR + g * 8;
#pragma unroll
        for (int f = 0; f < 4; ++f) {
          half8 h;
#pragma unroll
          for (int j = 0; j < 8; ++j) h[j] = (_Float16)kp[f * 32 + j];
          buf[u][f] = h;
        }
      }
    }
  };

  float rowmax[SROW * 4];   // running per-wave max; rows: i=s*4+r
#pragma unroll
  for (int i = 0; i < SROW * 4; ++i) rowmax[i] = -3.4e38f;

  half8 bA[2][4], bB[2][4];
  loadPair(0, bA);

#pragma unroll
  for (int grp = 0; grp < SLICES / 4; ++grp) {   // 4 groups of 4 slices
    loadPair(2 * grp + 1, bB);                   // prefetch pair 2grp+1

    f32x4v acc[4][SROW];
#pragma unroll
    for (int u = 0; u < 4; ++u)
#pragma unroll
      for (int s = 0; s < SROW; ++s) acc[u][s] = f32x4v{0.f, 0.f, 0.f, 0.f};

    // MFMA pair 2grp (slices 4grp, 4grp+1) from bA
#pragma unroll
    for (int u = 0; u < 2; ++u)
#pragma unroll
      for (int f = 0; f < 4; ++f)
#pragma unroll
        for (int s = 0; s < SROW; ++s)
          acc[u][s] = __builtin_amdgcn_mfma_f32_16x16x32_f16(aq[s][f], bA[u][f], acc[u][s], 0, 0, 0);

    if (grp < SLICES / 4 - 1) loadPair(2 * grp + 2, bA);  // prefetch next pair

    // MFMA pair 2grp+1 (slices 4grp+2, 4grp+3) from bB
#pragma unroll
    for (int u = 0; u < 2; ++u)
#pragma unroll
      for (int f = 0; f < 4; ++f)
#pragma unroll
        for (int s = 0; s < SROW; ++s)
          acc[u + 2][s] = __builtin_amdgcn_mfma_f32_16x16x32_f16(aq[s][f], bB[u][f], acc[u + 2][s], 0, 0, 0);

    // update running max (C layout: row = 4*g + r, col = key lane ln)
#pragma unroll
    for (int u = 0; u < 4; ++u)
#pragma unroll
      for (int s = 0; s < SROW; ++s)
#pragma unroll
        for (int r = 0; r < 4; ++r)
          rowmax[s * 4 + r] = fmaxf(rowmax[s * 4 + r], acc[u][s][r]);
#pragma unroll
    for (int d = 1; d < 16; d <<= 1)
#pragma unroll
      for (int i = 0; i < SROW * 4; ++i)
        rowmax[i] = fmaxf(rowmax[i], __shfl_xor(rowmax[i], d, 64));

    // emit this group's 4 slices against the running threshold
#pragma unroll
    for (int u = 0; u < 4; ++u) {
      const int keyg = key0 + (grp * 4 + u) * 16 + ln;
#pragma unroll
      for (int s = 0; s < SROW; ++s)
#pragma unroll
        for (int r = 0; r < 4; ++r)
          if (acc[u][s][r] >= rowmax[s * 4 + r] - EMIT_MARGIN) {
            const int q = s * 16 + g * 4 + r;  // row within this 32-row tile
            const int slot = atomicAdd(&lcnt[q], 1);
            if (slot < BLOCKCAP) lbuf[q][slot] = pack16(keyg, acc[u][s][r]);
          }
    }
  }

  // publish per-wave final max -> chunk max
  if (ln == 0) {
#pragma unroll
    for (int i = 0; i < SROW * 4; ++i)
      atomicMax(&lmax[(i >> 2) * 16 + g * 4 + (i & 3)], enc_f32(rowmax[i]));
  }
  __syncthreads();

  // ---- flush: fixed per-(query,chunk) region, plain stores ----
  const size_t qbase = (size_t)net * NQ + qt * QT;
  for (int j = tid; j < QT * BLOCKCAP; j += SCAN_WAVES * 64) {
    const int q = j >> 5, i = j & (BLOCKCAP - 1);
    const int cq = lcnt[q];
    if (i < (cq < BLOCKCAP ? cq : BLOCKCAP))
      cand[((qbase + q) * NCHUNK + chunk) * BLOCKCAP + i] = lbuf[q][i];
  }
  if (tid < QT) {
    cntb[(qbase + tid) * NCHUNK + chunk] = lcnt[tid];   // >BLOCKCAP => overflow
    cmaxb[(qbase + tid) * NCHUNK + chunk] = dec_f32(lmax[tid]);
  }
}

// ------------------------------- refine ------------------------------------
// one block (256 thr) per (query, net).  G = max stored chunk max; skip
// chunks with cmax < G-REL (provably irrelevant); stored-filter or per-chunk
// exact rescan (if overflowed); exact fp32 rescore of survivors; exact
// softmax + PV.
__global__ __launch_bounds__(256)
void refine_kernel(const float* __restrict__ qcur, const float* __restrict__ emb,
                   const int* __restrict__ cntb, const float* __restrict__ cmaxb,
                   const unsigned* __restrict__ cand, float* __restrict__ qnext) {
  const int q = blockIdx.x, net = blockIdx.y;
  const int tid = threadIdx.x, lane = tid & 63, w = tid >> 6;
  const int slot = net * NQ + q;
  __shared__ float qv[EDIM];
  __shared__ float osh[EDIM];
  __shared__ int ccnt[NCHUNK];
  __shared__ float cmax[NCHUNK];
  __shared__ int keys[SURV_CAP];
  __shared__ float exsc[SURV_CAP];
  __shared__ int nsurv;
  __shared__ float gmax_s;
  __shared__ float red[8];

  if (tid < EDIM) qv[tid] = 2.0f * qcur[(size_t)slot * EDIM + tid];
  if (tid < NCHUNK) {
    ccnt[tid] = cntb[(size_t)slot * NCHUNK + tid];
    cmax[tid] = cmaxb[(size_t)slot * NCHUNK + tid];
  }
  if (tid == 0) nsurv = 0;
  __syncthreads();
  if (tid == 0) {
    float gv = -3.4e38f;
    for (int c = 0; c < NCHUNK; ++c) gv = fmaxf(gv, cmax[c]);
    gmax_s = gv;
  }
  __syncthreads();
  const float G = gmax_s;

  // ---- collect survivors from relevant chunks ----
  for (int c = 0; c < NCHUNK; ++c) {
    if (cmax[c] < G - REL_MARGIN) continue;  // block-uniform: safe to skip
    const int cc = ccnt[c];
    if (cc <= BLOCKCAP) {
      if (tid < cc) {
        const unsigned pv = cand[((size_t)slot * NCHUNK + c) * BLOCKCAP + tid];
        if (dec16(pv) >= G - SEL_MARGIN) {
          const int i = atomicAdd(&nsurv, 1);
          if (i < SURV_CAP) keys[i] = (int)(pv >> 16);
        }
      }
    } else {
      // overflowed relevant chunk: exact fp32 rescan of its 1024 keys
      for (int k = c * KPC + tid; k < (c + 1) * KPC; k += 256) {
        const float* kr = emb + ((size_t)net * NKEY + k) * ESTR;
        float s = 0.f;
        for (int e = 0; e < EDIM; ++e) s += qv[e] * kr[e];
        if (s >= G - RESCAN_MARGIN) {
          const int i = atomicAdd(&nsurv, 1);
          if (i < SURV_CAP) keys[i] = k;
        }
      }
    }
  }
  __syncthreads();
  int m = nsurv < SURV_CAP ? nsurv : SURV_CAP;

  // ---- exact fp32 scores for the m survivors ----
  for (int j = w; j < m; j += 4) {
    const float* kr = emb + ((size_t)net * NKEY + keys[j]) * ESTR;
    float p2 = qv[2 * lane] * kr[2 * lane] + qv[2 * lane + 1] * kr[2 * lane + 1];
#pragma unroll
    for (int d = 32; d; d >>= 1) p2 += __shfl_xor(p2, d, 64);
    if (lane == 0) exsc[j] = p2;
  }
  __syncthreads();
  if (w == 0) {
    float em = -3.4e38f;
    for (int j = lane; j < m; j += 64) em = fmaxf(em, exsc[j]);
#pragma unroll
    for (int d = 32; d; d >>= 1) em = fmaxf(em, __shfl_xor(em, d, 64));
    if (lane == 0) red[0] = em;
  }
  __syncthreads();
  const float em = red[0];
  for (int j = tid; j < m; j += 256) exsc[j] = expf(exsc[j] - em);
  __syncthreads();
  if (w == 0) {
    float l = 0.f;
    for (int j = lane; j < m; j += 64) l += exsc[j];
#pragma unroll
    for (int d = 32; d; d >>= 1) l += __shfl_xor(l, d, 64);
    if (lane == 0) red[1] = l;
  }
  __syncthreads();
  // ---- exact PV over survivors ----
  const float inv = 1.0f / red[1];
  const int e = tid & 127, hf = tid >> 7;
  float acc = 0.f;
  for (int j = hf; j < m; j += 2)
    acc += exsc[j] * emb[((size_t)net * NKEY + keys[j]) * ESTR + e];
  if (hf) osh[e] = acc;
  __syncthreads();
  if (!hf) qnext[(size_t)slot * EDIM + e] = (acc + osh[e]) * inv;
}

// ------------------------------- head --------------------------------------
__global__ __launch_bounds__(64)
void head_kernel(const float* __restrict__ qf, const float* __restrict__ Wl,
                 const float* __restrict__ bl, float* __restrict__ out) {
  const int b = blockIdx.x, lane = threadIdx.x;
  float acc[10];
#pragma unroll
  for (int c = 0; c < 10; ++c) acc[c] = 0.f;
  for (int t = lane; t < NNET * EDIM; t += 64) {
    float z = qf[((size_t)(t >> 7) * NQ + b) * EDIM + (t & 127)];
    z = fmaxf(z, 0.f);
    const float* wr = Wl + t * 10;
#pragma unroll
    for (int c = 0; c < 10; ++c) acc[c] += z * wr[c];
  }
#pragma unroll
  for (int d = 32; d; d >>= 1)
#pragma unroll
    for (int c = 0; c < 10; ++c) acc[c] += __shfl_xor(acc[c], d, 64);
  if (lane == 0) {
    float lg[10], mxv = -3.4e38f;
#pragma unroll
    for (int c = 0; c < 10; ++c) {
      lg[c] = acc[c] + bl[c];
      mxv = fmaxf(mxv, lg[c]);
    }
    float s = 0.f;
#pragma unroll
    for (int c = 0; c < 10; ++c) s += expf(lg[c] - mxv);
    float lse = mxv + logf(s);
#pragma unroll
    for (int c = 0; c < 10; ++c) out[b * 10 + c] = lg[c] - lse;
  }
}

// ------------------------------- launch ------------------------------------
extern "C" void kernel_launch(void* const* d_in, const int* in_sizes, int n_in,
                              void* d_out, int out_size, void* d_ws, size_t ws_size,
                              hipStream_t stream) {
  (void)in_sizes; (void)n_in; (void)out_size;
  const float* x   = (const float*)d_in[0];
  const float* emb = (const float*)d_in[1];
  const float* We  = (const float*)d_in[2];
  const float* be  = (const float*)d_in[3];
  const float* Wl  = (const float*)d_in[4];
  const float* bl  = (const float*)d_in[5];
  float* out = (float*)d_out;

  char* p = (char*)d_ws;
  float* q0 = (float*)p;    p += (size_t)NNET * NQ * EDIM * 4;
  float* q1 = (float*)p;    p += (size_t)NNET * NQ * EDIM * 4;
  int* cntb = (int*)p;      p += (size_t)NNET * NQ * NCHUNK * 4;
  float* cmaxb = (float*)p; p += (size_t)NNET * NQ * NCHUNK * 4;
  unsigned* cand = (unsigned*)p; p += (size_t)NNET * NQ * NCHUNK * BLOCKCAP * 4;
  _Float16* kh = (_Float16*)p;
  const bool f16k =
      ((size_t)(p - (char*)d_ws) + (size_t)NNET * NKEY * EDIM * 2) <= ws_size;

  enc_kernel<<<dim3(NQ), dim3(128), 0, stream>>>(x, We, be, q0);
  if (f16k)
    keyprep_kernel<<<dim3(4096), dim3(256), 0, stream>>>(emb, kh);

  const int nblocks = NNET * NCHUNK * (NQ / QT);  // 1024
  float* qa = q0;
  float* qb = q1;
  for (int step = 0; step < 4; ++step) {
    if (f16k)
      scan_kernel<true><<<dim3(nblocks), dim3(SCAN_WAVES * 64), 0, stream>>>(
          qa, emb, kh, cntb, cmaxb, cand);
    else
      scan_kernel<false><<<dim3(nblocks), dim3(SCAN_WAVES * 64), 0, stream>>>(
          qa, emb, (const _Float16*)nullptr, cntb, cmaxb, cand);
    refine_kernel<<<dim3(NQ, NNET), dim3(256), 0, stream>>>(qa, emb, cntb, cmaxb, cand, qb);
    float* t = qa; qa = qb; qb = t;
  }
  head_kernel<<<dim3(NQ), dim3(64), 0, stream>>>(qa, Wl, bl, out);
}

// Round 11
// 382.760 us; speedup vs baseline: 1.3970x; 1.3970x over previous
//
#include <hip/hip_runtime.h>
#include <hip/hip_bf16.h>
#include <cstdint>
#include <cstddef>

// ---------------------------------------------------------------------------
// HopfieldModel: z = x@W_enc; 4x { q <- softmax(2 q K^T) K } per network;
// out = log_softmax(relu(concat q) @ W_lin + b_lin)
//
// scan v3.1 (fp16 MFMA, software-pipelined single pass):
//   - pairs of 16-key slices double-buffered: load pair p+1 while MFMA pair p.
//   - emit per 4-slice group against a running PER-WAVE threshold
//     (run_max <= G  =>  every key with s >= G-9.5 is emitted).
//   - BLOCKCAP=64 (round-10 lesson: per-wave anchoring emits ~20-25 per
//     (query,chunk); BLOCKCAP=32 overflowed constantly -> refine rescan
//     storms at 137us with FETCH=105MB).
//   - dispatch-window XCD swizzle: wg = 64*window + 8*qt + xcd.
// refine: G = max stored chunk max; skip chunks with cmax < G-9.75; stored
//   candidates filtered at G-9.5; overflowed relevant chunks get a WAVE-
//   PARALLEL exact fp32 rescan of JUST that 1024-key chunk (lane=2 elems +
//   butterfly; round-10 lesson: the per-thread serial-dot rescan was 512
//   dependent loads/thread); survivors exactly rescored fp32; exact
//   softmax + PV.
// ---------------------------------------------------------------------------

#define NNET 4
#define NQ   256
#define EDIM 128
#define NKEY 32768
#define ESTR 129              // embeddings row stride (col 128 dropped)
#define QT   32               // q rows per scan block
#define NCHUNK 32
#define KPC  (NKEY/NCHUNK)    // 1024 keys per chunk
#define SCAN_WAVES 4
#define KPW  (KPC/SCAN_WAVES) // 256 keys per wave
#define SLICES (KPW/16)       // 16 slices of 16 keys
#define SROW (QT/16)          // 2 row-tiles of 16 q rows
#define BLOCKCAP 64           // cand slots per (query, chunk); log2 = 6
#define SURV_CAP 512
#define EMIT_MARGIN 10.0f     // emission band below running wave max
#define SEL_MARGIN  9.5f      // stored-score filter below global max
#define REL_MARGIN  9.75f     // chunk relevance: cmax >= G - REL
#define RESCAN_MARGIN 10.0f   // exact-score filter for rescanned chunks

typedef _Float16 half8 __attribute__((ext_vector_type(8)));
typedef float f32x4v __attribute__((ext_vector_type(4)));

__device__ __forceinline__ float dec16(unsigned v) {
  _Float16 h = __builtin_bit_cast(_Float16, (unsigned short)(v & 0xFFFFu));
  return (float)h;
}
__device__ __forceinline__ unsigned pack16(int key, float s) {
  unsigned short hb = __builtin_bit_cast(unsigned short, (_Float16)s);
  return ((unsigned)key << 16) | (unsigned)hb;
}
__device__ __forceinline__ unsigned enc_f32(float f) {
  unsigned u = __float_as_uint(f);
  return (u & 0x80000000u) ? ~u : (u | 0x80000000u);  // order-preserving
}
__device__ __forceinline__ float dec_f32(unsigned e) {
  unsigned u = (e & 0x80000000u) ? (e & 0x7FFFFFFFu) : ~e;
  return __uint_as_float(u);
}

// --------------------------- encoder: z = x@We + be -------------------------
__global__ __launch_bounds__(128)
void enc_kernel(const float* __restrict__ x, const float* __restrict__ We,
                const float* __restrict__ be, float* __restrict__ q0) {
  const int b = blockIdx.x, tid = threadIdx.x;
  __shared__ float xs[784];
  for (int i = tid; i < 784; i += 128) xs[i] = x[b * 784 + i];
  __syncthreads();
  float acc = be[tid];
  for (int i = 0; i < 784; ++i) acc += xs[i] * We[i * EDIM + tid];
#pragma unroll
  for (int n = 0; n < NNET; ++n) q0[((size_t)n * NQ + b) * EDIM + tid] = acc;
}

// ------------------- keyprep: embeddings f32 -> fp16 (drop col 128) --------
typedef _Float16 half4v __attribute__((ext_vector_type(4)));
__global__ __launch_bounds__(256)
void keyprep_kernel(const float* __restrict__ emb, _Float16* __restrict__ kh) {
  const size_t quads = (size_t)NNET * NKEY * EDIM / 4;
  for (size_t i4 = (size_t)blockIdx.x * 256 + threadIdx.x; i4 < quads;
       i4 += (size_t)gridDim.x * 256) {
    const size_t row = i4 >> 5;
    const int col = (int)(i4 & 31) * 4;
    const float* src = emb + row * ESTR + col;
    half4v h;
#pragma unroll
    for (int j = 0; j < 4; ++j) h[j] = (_Float16)src[j];
    *(half4v*)(kh + i4 * 4) = h;
  }
}

// ------------------------------- scan --------------------------------------
// 1024 blocks (1D), 256 threads = 4 waves, each wave owns 256 keys.
// Block remap: wg = 64*window + 8*qt + xcd; chunk-group c = 8*window + xcd.
template <bool F16K>
__global__ __launch_bounds__(SCAN_WAVES * 64)
void scan_kernel(const float* __restrict__ qcur, const float* __restrict__ emb,
                 const _Float16* __restrict__ keysh,
                 int* __restrict__ cntb, float* __restrict__ cmaxb,
                 unsigned* __restrict__ cand) {
  const int wg = blockIdx.x;
  const int window = wg >> 6;        // 16 windows of 64 blocks
  const int within = wg & 63;
  const int xcd = within & 7;
  const int qt = within >> 3;        // 0..7
  const int c = window * 8 + xcd;    // 0..127
  const int net = c >> 5, chunk = c & 31;

  const int tid = threadIdx.x;
  const int lane = tid & 63;
  const int g = lane >> 4, ln = lane & 15;

  __shared__ unsigned lmax[QT];
  __shared__ int lcnt[QT];
  __shared__ unsigned lbuf[QT][BLOCKCAP];
  if (tid < QT) { lmax[tid] = enc_f32(-3.4e38f); lcnt[tid] = 0; }

  // Q A-fragments (16x16x32: lane holds row m=lane&15, k = 8*(lane>>4)+j),
  // beta=2 folded into q.
  half8 aq[SROW][4];
  {
    const float* qb = qcur + ((size_t)net * NQ + qt * QT) * EDIM;
#pragma unroll
    for (int s = 0; s < SROW; ++s)
#pragma unroll
      for (int f = 0; f < 4; ++f) {
        const float* p = qb + (s * 16 + ln) * EDIM + f * 32 + g * 8;
        half8 h;
#pragma unroll
        for (int j = 0; j < 8; ++j) h[j] = (_Float16)(2.0f * p[j]);
        aq[s][f] = h;
      }
  }
  __syncthreads();

  const int w = tid >> 6;
  const int key0 = chunk * KPC + w * KPW;

  // load one PAIR of slices (2*p, 2*p+1) into buf[2][4] (8 x 16B loads)
  auto loadPair = [&](int p, half8 buf[2][4]) {
#pragma unroll
    for (int u = 0; u < 2; ++u) {
      const int sl = 2 * p + u;
      const size_t keyrow = (size_t)net * NKEY + key0 + sl * 16 + ln;
      if constexpr (F16K) {
        const _Float16* kp = keysh + keyrow * EDIM + g * 8;
#pragma unroll
        for (int f = 0; f < 4; ++f) buf[u][f] = *(const half8*)(kp + f * 32);
      } else {
        const float* kp = emb + keyrow * ESTR + g * 8;
#pragma unroll
        for (int f = 0; f < 4; ++f) {
          half8 h;
#pragma unroll
          for (int j = 0; j < 8; ++j) h[j] = (_Float16)kp[f * 32 + j];
          buf[u][f] = h;
        }
      }
    }
  };

  float rowmax[SROW * 4];   // running per-wave max; rows: i=s*4+r
#pragma unroll
  for (int i = 0; i < SROW * 4; ++i) rowmax[i] = -3.4e38f;

  half8 bA[2][4], bB[2][4];
  loadPair(0, bA);

#pragma unroll
  for (int grp = 0; grp < SLICES / 4; ++grp) {   // 4 groups of 4 slices
    loadPair(2 * grp + 1, bB);                   // prefetch pair 2grp+1

    f32x4v acc[4][SROW];
#pragma unroll
    for (int u = 0; u < 4; ++u)
#pragma unroll
      for (int s = 0; s < SROW; ++s) acc[u][s] = f32x4v{0.f, 0.f, 0.f, 0.f};

    // MFMA pair 2grp (slices 4grp, 4grp+1) from bA
#pragma unroll
    for (int u = 0; u < 2; ++u)
#pragma unroll
      for (int f = 0; f < 4; ++f)
#pragma unroll
        for (int s = 0; s < SROW; ++s)
          acc[u][s] = __builtin_amdgcn_mfma_f32_16x16x32_f16(aq[s][f], bA[u][f], acc[u][s], 0, 0, 0);

    if (grp < SLICES / 4 - 1) loadPair(2 * grp + 2, bA);  // prefetch next pair

    // MFMA pair 2grp+1 (slices 4grp+2, 4grp+3) from bB
#pragma unroll
    for (int u = 0; u < 2; ++u)
#pragma unroll
      for (int f = 0; f < 4; ++f)
#pragma unroll
        for (int s = 0; s < SROW; ++s)
          acc[u + 2][s] = __builtin_amdgcn_mfma_f32_16x16x32_f16(aq[s][f], bB[u][f], acc[u + 2][s], 0, 0, 0);

    // update running max (C layout: row = 4*g + r, col = key lane ln)
#pragma unroll
    for (int u = 0; u < 4; ++u)
#pragma unroll
      for (int s = 0; s < SROW; ++s)
#pragma unroll
        for (int r = 0; r < 4; ++r)
          rowmax[s * 4 + r] = fmaxf(rowmax[s * 4 + r], acc[u][s][r]);
#pragma unroll
    for (int d = 1; d < 16; d <<= 1)
#pragma unroll
      for (int i = 0; i < SROW * 4; ++i)
        rowmax[i] = fmaxf(rowmax[i], __shfl_xor(rowmax[i], d, 64));

    // emit this group's 4 slices against the running threshold
#pragma unroll
    for (int u = 0; u < 4; ++u) {
      const int keyg = key0 + (grp * 4 + u) * 16 + ln;
#pragma unroll
      for (int s = 0; s < SROW; ++s)
#pragma unroll
        for (int r = 0; r < 4; ++r)
          if (acc[u][s][r] >= rowmax[s * 4 + r] - EMIT_MARGIN) {
            const int q = s * 16 + g * 4 + r;  // row within this 32-row tile
            const int slot = atomicAdd(&lcnt[q], 1);
            if (slot < BLOCKCAP) lbuf[q][slot] = pack16(keyg, acc[u][s][r]);
          }
    }
  }

  // publish per-wave final max -> chunk max
  if (ln == 0) {
#pragma unroll
    for (int i = 0; i < SROW * 4; ++i)
      atomicMax(&lmax[(i >> 2) * 16 + g * 4 + (i & 3)], enc_f32(rowmax[i]));
  }
  __syncthreads();

  // ---- flush: fixed per-(query,chunk) region, plain stores ----
  const size_t qbase = (size_t)net * NQ + qt * QT;
  for (int j = tid; j < QT * BLOCKCAP; j += SCAN_WAVES * 64) {
    const int q = j >> 6, i = j & (BLOCKCAP - 1);
    const int cq = lcnt[q];
    if (i < (cq < BLOCKCAP ? cq : BLOCKCAP))
      cand[((qbase + q) * NCHUNK + chunk) * BLOCKCAP + i] = lbuf[q][i];
  }
  if (tid < QT) {
    cntb[(qbase + tid) * NCHUNK + chunk] = lcnt[tid];   // >BLOCKCAP => overflow
    cmaxb[(qbase + tid) * NCHUNK + chunk] = dec_f32(lmax[tid]);
  }
}

// ------------------------------- refine ------------------------------------
// one block (256 thr) per (query, net).  G = max stored chunk max; skip
// chunks with cmax < G-REL (provably irrelevant); stored-filter or WAVE-
// PARALLEL per-chunk exact rescan (if overflowed); exact fp32 rescore of
// survivors; exact softmax + PV.
__global__ __launch_bounds__(256)
void refine_kernel(const float* __restrict__ qcur, const float* __restrict__ emb,
                   const int* __restrict__ cntb, const float* __restrict__ cmaxb,
                   const unsigned* __restrict__ cand, float* __restrict__ qnext) {
  const int q = blockIdx.x, net = blockIdx.y;
  const int tid = threadIdx.x, lane = tid & 63, w = tid >> 6;
  const int slot = net * NQ + q;
  __shared__ float qv[EDIM];
  __shared__ float osh[EDIM];
  __shared__ int ccnt[NCHUNK];
  __shared__ float cmax[NCHUNK];
  __shared__ int keys[SURV_CAP];
  __shared__ float exsc[SURV_CAP];
  __shared__ int nsurv;
  __shared__ float gmax_s;
  __shared__ float red[8];

  if (tid < EDIM) qv[tid] = 2.0f * qcur[(size_t)slot * EDIM + tid];
  if (tid < NCHUNK) {
    ccnt[tid] = cntb[(size_t)slot * NCHUNK + tid];
    cmax[tid] = cmaxb[(size_t)slot * NCHUNK + tid];
  }
  if (tid == 0) nsurv = 0;
  __syncthreads();
  if (tid == 0) {
    float gv = -3.4e38f;
    for (int c = 0; c < NCHUNK; ++c) gv = fmaxf(gv, cmax[c]);
    gmax_s = gv;
  }
  __syncthreads();
  const float G = gmax_s;

  // ---- collect survivors from relevant chunks ----
  for (int c = 0; c < NCHUNK; ++c) {
    if (cmax[c] < G - REL_MARGIN) continue;  // block-uniform: safe to skip
    const int cc = ccnt[c];
    if (cc <= BLOCKCAP) {
      if (tid < cc) {
        const unsigned pv = cand[((size_t)slot * NCHUNK + c) * BLOCKCAP + tid];
        if (dec16(pv) >= G - SEL_MARGIN) {
          const int i = atomicAdd(&nsurv, 1);
          if (i < SURV_CAP) keys[i] = (int)(pv >> 16);
        }
      }
    } else {
      // overflowed relevant chunk: wave-parallel exact fp32 rescan
      // (each wave takes every-4th key; lane covers 2 elems + butterfly)
      for (int k = c * KPC + w; k < (c + 1) * KPC; k += 4) {
        const float* kr = emb + ((size_t)net * NKEY + k) * ESTR;
        float p = qv[2 * lane] * kr[2 * lane] + qv[2 * lane + 1] * kr[2 * lane + 1];
#pragma unroll
        for (int d = 32; d; d >>= 1) p += __shfl_xor(p, d, 64);
        if (lane == 0 && p >= G - RESCAN_MARGIN) {
          const int i = atomicAdd(&nsurv, 1);
          if (i < SURV_CAP) keys[i] = k;
        }
      }
    }
  }
  __syncthreads();
  int m = nsurv < SURV_CAP ? nsurv : SURV_CAP;

  // ---- exact fp32 scores for the m survivors ----
  for (int j = w; j < m; j += 4) {
    const float* kr = emb + ((size_t)net * NKEY + keys[j]) * ESTR;
    float p2 = qv[2 * lane] * kr[2 * lane] + qv[2 * lane + 1] * kr[2 * lane + 1];
#pragma unroll
    for (int d = 32; d; d >>= 1) p2 += __shfl_xor(p2, d, 64);
    if (lane == 0) exsc[j] = p2;
  }
  __syncthreads();
  if (w == 0) {
    float em = -3.4e38f;
    for (int j = lane; j < m; j += 64) em = fmaxf(em, exsc[j]);
#pragma unroll
    for (int d = 32; d; d >>= 1) em = fmaxf(em, __shfl_xor(em, d, 64));
    if (lane == 0) red[0] = em;
  }
  __syncthreads();
  const float em = red[0];
  for (int j = tid; j < m; j += 256) exsc[j] = expf(exsc[j] - em);
  __syncthreads();
  if (w == 0) {
    float l = 0.f;
    for (int j = lane; j < m; j += 64) l += exsc[j];
#pragma unroll
    for (int d = 32; d; d >>= 1) l += __shfl_xor(l, d, 64);
    if (lane == 0) red[1] = l;
  }
  __syncthreads();
  // ---- exact PV over survivors ----
  const float inv = 1.0f / red[1];
  const int e = tid & 127, hf = tid >> 7;
  float acc = 0.f;
  for (int j = hf; j < m; j += 2)
    acc += exsc[j] * emb[((size_t)net * NKEY + keys[j]) * ESTR + e];
  if (hf) osh[e] = acc;
  __syncthreads();
  if (!hf) qnext[(size_t)slot * EDIM + e] = (acc + osh[e]) * inv;
}

// ------------------------------- head --------------------------------------
__global__ __launch_bounds__(64)
void head_kernel(const float* __restrict__ qf, const float* __restrict__ Wl,
                 const float* __restrict__ bl, float* __restrict__ out) {
  const int b = blockIdx.x, lane = threadIdx.x;
  float acc[10];
#pragma unroll
  for (int c = 0; c < 10; ++c) acc[c] = 0.f;
  for (int t = lane; t < NNET * EDIM; t += 64) {
    float z = qf[((size_t)(t >> 7) * NQ + b) * EDIM + (t & 127)];
    z = fmaxf(z, 0.f);
    const float* wr = Wl + t * 10;
#pragma unroll
    for (int c = 0; c < 10; ++c) acc[c] += z * wr[c];
  }
#pragma unroll
  for (int d = 32; d; d >>= 1)
#pragma unroll
    for (int c = 0; c < 10; ++c) acc[c] += __shfl_xor(acc[c], d, 64);
  if (lane == 0) {
    float lg[10], mxv = -3.4e38f;
#pragma unroll
    for (int c = 0; c < 10; ++c) {
      lg[c] = acc[c] + bl[c];
      mxv = fmaxf(mxv, lg[c]);
    }
    float s = 0.f;
#pragma unroll
    for (int c = 0; c < 10; ++c) s += expf(lg[c] - mxv);
    float lse = mxv + logf(s);
#pragma unroll
    for (int c = 0; c < 10; ++c) out[b * 10 + c] = lg[c] - lse;
  }
}

// ------------------------------- launch ------------------------------------
extern "C" void kernel_launch(void* const* d_in, const int* in_sizes, int n_in,
                              void* d_out, int out_size, void* d_ws, size_t ws_size,
                              hipStream_t stream) {
  (void)in_sizes; (void)n_in; (void)out_size;
  const float* x   = (const float*)d_in[0];
  const float* emb = (const float*)d_in[1];
  const float* We  = (const float*)d_in[2];
  const float* be  = (const float*)d_in[3];
  const float* Wl  = (const float*)d_in[4];
  const float* bl  = (const float*)d_in[5];
  float* out = (float*)d_out;

  char* p = (char*)d_ws;
  float* q0 = (float*)p;    p += (size_t)NNET * NQ * EDIM * 4;
  float* q1 = (float*)p;    p += (size_t)NNET * NQ * EDIM * 4;
  int* cntb = (int*)p;      p += (size_t)NNET * NQ * NCHUNK * 4;
  float* cmaxb = (float*)p; p += (size_t)NNET * NQ * NCHUNK * 4;
  unsigned* cand = (unsigned*)p; p += (size_t)NNET * NQ * NCHUNK * BLOCKCAP * 4;
  _Float16* kh = (_Float16*)p;
  const bool f16k =
      ((size_t)(p - (char*)d_ws) + (size_t)NNET * NKEY * EDIM * 2) <= ws_size;

  enc_kernel<<<dim3(NQ), dim3(128), 0, stream>>>(x, We, be, q0);
  if (f16k)
    keyprep_kernel<<<dim3(4096), dim3(256), 0, stream>>>(emb, kh);

  const int nblocks = NNET * NCHUNK * (NQ / QT);  // 1024
  float* qa = q0;
  float* qb = q1;
  for (int step = 0; step < 4; ++step) {
    if (f16k)
      scan_kernel<true><<<dim3(nblocks), dim3(SCAN_WAVES * 64), 0, stream>>>(
          qa, emb, kh, cntb, cmaxb, cand);
    else
      scan_kernel<false><<<dim3(nblocks), dim3(SCAN_WAVES * 64), 0, stream>>>(
          qa, emb, (const _Float16*)nullptr, cntb, cmaxb, cand);
    refine_kernel<<<dim3(NQ, NNET), dim3(256), 0, stream>>>(qa, emb, cntb, cmaxb, cand, qb);
    float* t = qa; qa = qb; qb = t;
  }
  head_kernel<<<dim3(NQ), dim3(64), 0, stream>>>(qa, Wl, bl, out);
}